// Round 1
// baseline (838.685 us; speedup 1.0000x reference)
//
#include <hip/hip_runtime.h>

#define F 64  // F_IN == F_OUT == 64

// ---------------------------------------------------------------------------
// Kernel 1: edge scatter-add.  agg[dst] += x[src] for each edge.
// 16 lanes per edge, each lane handles 4 consecutive features via float4
// gather + 4 scalar global fp32 atomics (HW global_atomic_add_f32, no return).
// A wave covers 4 edges; gathers are 256B-contiguous per edge.
// ---------------------------------------------------------------------------
__global__ __launch_bounds__(256) void scatter_add_kernel(
    const float* __restrict__ x,
    const int* __restrict__ edge_index,  // [2, n_edges]: row0=src, row1=dst
    float* __restrict__ agg,
    int n_edges) {
  long long gid = (long long)blockIdx.x * blockDim.x + threadIdx.x;
  int e = (int)(gid >> 4);
  if (e >= n_edges) return;
  int fg = ((int)gid & 15) * 4;

  int src = edge_index[e];
  int dst = edge_index[n_edges + e];

  const float4 v = *(const float4*)(x + (long long)src * F + fg);
  float* base = agg + (long long)dst * F + fg;
  atomicAdd(base + 0, v.x);
  atomicAdd(base + 1, v.y);
  atomicAdd(base + 2, v.z);
  atomicAdd(base + 3, v.w);
}

// ---------------------------------------------------------------------------
// Kernel 2: out = relu(agg @ W_rel^T + b_rel + x @ W_root^T)
// W_rel, W_root are [F_OUT, F_IN] row-major; we stage them TRANSPOSED in LDS
// so lane o reads WT[k*F + o] (consecutive across lanes -> 2-way bank alias,
// free on gfx950).  Row data staged in LDS and read as wave-uniform broadcast.
// 256 threads: o = tid&63, slot = tid>>6 (4 rows in flight), 16 rows/block.
// LDS: 2*16KB (weights) + 2*1KB (rows) = 34KB -> ~4 blocks/CU.
// ---------------------------------------------------------------------------
__global__ __launch_bounds__(256) void gemm_fused_kernel(
    const float* __restrict__ agg,
    const float* __restrict__ x,
    const float* __restrict__ W_rel,   // [F,F]
    const float* __restrict__ b_rel,   // [F]
    const float* __restrict__ W_root,  // [F,F]
    float* __restrict__ out,
    int n_nodes) {
  __shared__ float WrT[F * F];
  __shared__ float WoT[F * F];
  __shared__ float arow[4][F];
  __shared__ float xrow[4][F];

  const int t = threadIdx.x;

  // Coalesced read of W (i = o*F + k), transposed store to LDS.
  for (int i = t; i < F * F; i += 256) {
    int o = i >> 6;
    int k = i & 63;
    WrT[k * F + o] = W_rel[i];
    WoT[k * F + o] = W_root[i];
  }
  __syncthreads();

  const int o = t & 63;
  const int slot = t >> 6;
  const float bias = b_rel[o];
  const int row_base = blockIdx.x * 16;

  for (int rr = 0; rr < 16; rr += 4) {
    const int r0 = row_base + rr;
    // stage 4 rows of agg and x (each thread loads one element of each)
    {
      const int r = r0 + slot;
      if (r < n_nodes) {
        arow[slot][o] = agg[(long long)r * F + o];
        xrow[slot][o] = x[(long long)r * F + o];
      }
    }
    __syncthreads();

    const int r = r0 + slot;
    if (r < n_nodes) {
      float acc = bias;
#pragma unroll
      for (int k = 0; k < F; ++k) {
        acc += arow[slot][k] * WrT[k * F + o];
        acc += xrow[slot][k] * WoT[k * F + o];
      }
      out[(long long)r * F + o] = fmaxf(acc, 0.0f);
    }
    __syncthreads();
  }
}

extern "C" void kernel_launch(void* const* d_in, const int* in_sizes, int n_in,
                              void* d_out, int out_size, void* d_ws, size_t ws_size,
                              hipStream_t stream) {
  const float* x      = (const float*)d_in[0];  // [N, 64]
  const float* W_rel  = (const float*)d_in[1];  // [64, 64]
  const float* b_rel  = (const float*)d_in[2];  // [64]
  const float* W_root = (const float*)d_in[3];  // [64, 64]
  const int* edge_index = (const int*)d_in[4];  // [2, E]

  const int n_nodes = in_sizes[0] / F;
  const int n_edges = in_sizes[4] / 2;

  float* agg = (float*)d_ws;  // [N, 64] scratch accumulator
  float* out = (float*)d_out;

  // Zero the accumulator (ws is re-poisoned to 0xAA before every launch).
  hipMemsetAsync(agg, 0, (size_t)n_nodes * F * sizeof(float), stream);

  // Scatter-add: 16 threads per edge.
  {
    long long total = (long long)n_edges * 16;
    int block = 256;
    int grid = (int)((total + block - 1) / block);
    scatter_add_kernel<<<grid, block, 0, stream>>>(x, edge_index, agg, n_edges);
  }

  // Fused GEMM + bias + ReLU: 16 rows per block.
  {
    int block = 256;
    int grid = (n_nodes + 15) / 16;
    gemm_fused_kernel<<<grid, block, 0, stream>>>(agg, x, W_rel, b_rel, W_root,
                                                  out, n_nodes);
  }
}

// Round 2
// 297.244 us; speedup vs baseline: 2.8215x; 2.8215x over previous
//
#include <hip/hip_runtime.h>

#define F 64  // F_IN == F_OUT == 64

// ---------------------------------------------------------------------------
// CSR-build + pull-gather GraphConv.
// R1 showed push-scatter fp32 atomics are the wall: 51.2M atomics -> 819 MB
// HBM write-through (16 B/atomic), 682 us, VALUBusy 1%.  We build a CSR
// (dst -> list of src) with 1.6M *int* atomics, then pull-gather with zero
// float atomics and fuse the gather with the GEMM+bias+ReLU.
// ---------------------------------------------------------------------------

// 1) degree count: deg[dst]++ per edge
__global__ __launch_bounds__(256) void count_kernel(
    const int* __restrict__ edge_index, int* __restrict__ deg, int n_edges) {
  int e = blockIdx.x * 256 + threadIdx.x;
  if (e < n_edges) atomicAdd(&deg[edge_index[n_edges + e]], 1);
}

// 2a) per-block exclusive scan (256 elems/block) + block totals
__global__ __launch_bounds__(256) void scan1_kernel(
    const int* __restrict__ deg, int* __restrict__ offs,
    int* __restrict__ partials, int n) {
  __shared__ int tmp[256];
  const int t = threadIdx.x;
  const int i = blockIdx.x * 256 + t;
  int v = (i < n) ? deg[i] : 0;
  tmp[t] = v;
  __syncthreads();
  for (int d = 1; d < 256; d <<= 1) {
    int add = (t >= d) ? tmp[t - d] : 0;
    __syncthreads();
    tmp[t] += add;
    __syncthreads();
  }
  if (i < n) offs[i] = tmp[t] - v;  // exclusive within block
  if (t == 255) partials[blockIdx.x] = tmp[255];
}

// 2b) scan the block totals (G <= 256 blocks => single workgroup)
__global__ __launch_bounds__(256) void scan2_kernel(int* __restrict__ partials,
                                                    int G) {
  __shared__ int tmp[256];
  const int t = threadIdx.x;
  int v = (t < G) ? partials[t] : 0;
  tmp[t] = v;
  __syncthreads();
  for (int d = 1; d < 256; d <<= 1) {
    int add = (t >= d) ? tmp[t - d] : 0;
    __syncthreads();
    tmp[t] += add;
    __syncthreads();
  }
  if (t < G) partials[t] = tmp[t] - v;  // exclusive block base
}

// 2c) add block bases; produce offs[] and cursor[] (fill pointers)
__global__ __launch_bounds__(256) void scan3_kernel(
    int* __restrict__ offs, const int* __restrict__ partials,
    int* __restrict__ cursor, int n, int n_edges) {
  int i = blockIdx.x * 256 + threadIdx.x;
  if (i < n) {
    int v = offs[i] + partials[i >> 8];
    offs[i] = v;
    cursor[i] = v;
  }
  if (i == 0) offs[n] = n_edges;
}

// 3) fill the per-dst source lists
__global__ __launch_bounds__(256) void fill_kernel(
    const int* __restrict__ edge_index, int* __restrict__ cursor,
    int* __restrict__ esrc, int n_edges) {
  int e = blockIdx.x * 256 + threadIdx.x;
  if (e < n_edges) {
    int src = edge_index[e];
    int dst = edge_index[n_edges + e];
    int pos = atomicAdd(&cursor[dst], 1);
    esrc[pos] = src;
  }
}

// 4) fused pull-gather + GEMM + bias + ReLU.
// One wave per node (iterating NPW nodes); lane o owns output feature o and
// holds row o of W_rel and W_root in VGPRs (2*64 = 128 VGPRs, coalesced
// load: lane o reads a contiguous 256B row).  Gather: lane o accumulates
// feature o over the node's neighbor list -- each neighbor is one coalesced
// 256B wave read, L2/L3 resident (x = 12.8 MB).  The aggregated row and the
// node's own row round-trip through per-wave LDS so every lane can read all
// 64 k-values as float4 broadcasts (same-address -> conflict-free).
#define NPW 16  // nodes per wave (amortizes the 512B/lane weight load)
__global__ __launch_bounds__(256) void pull_gemm_kernel(
    const float* __restrict__ x,
    const float* __restrict__ W_rel,   // [F,F] row-major
    const float* __restrict__ b_rel,   // [F]
    const float* __restrict__ W_root,  // [F,F] row-major
    const int* __restrict__ offs,      // [N+1]
    const int* __restrict__ esrc,      // [E]
    float* __restrict__ out, int n_nodes) {
  __shared__ float aw[4 * F];
  __shared__ float xw[4 * F];
  const int t = threadIdx.x;
  const int o = t & 63;
  const int w = t >> 6;

  // lane o: row o of each weight matrix into registers (fully unrolled)
  float wr[F], wo[F];
#pragma unroll
  for (int k = 0; k < F; k += 4) {
    float4 a = *(const float4*)(W_rel + o * F + k);
    wr[k] = a.x; wr[k + 1] = a.y; wr[k + 2] = a.z; wr[k + 3] = a.w;
    float4 b = *(const float4*)(W_root + o * F + k);
    wo[k] = b.x; wo[k + 1] = b.y; wo[k + 2] = b.z; wo[k + 3] = b.w;
  }
  const float bias = b_rel[o];

  const int node0 = (blockIdx.x * 4 + w) * NPW;
  for (int nn = 0; nn < NPW; ++nn) {
    const int i = node0 + nn;            // wave-uniform
    if (i >= n_nodes) break;             // uniform branch, no divergence

    const int start = offs[i];
    const int end = offs[i + 1];
    float acc = 0.0f;
    int j = start;
    for (; j + 4 <= end; j += 4) {       // 4 independent rows in flight
      int s0 = esrc[j], s1 = esrc[j + 1], s2 = esrc[j + 2], s3 = esrc[j + 3];
      float v0 = x[(long long)s0 * F + o];
      float v1 = x[(long long)s1 * F + o];
      float v2 = x[(long long)s2 * F + o];
      float v3 = x[(long long)s3 * F + o];
      acc += v0 + v1 + v2 + v3;
    }
    for (; j < end; ++j) acc += x[(long long)esrc[j] * F + o];

    const float xi = x[(long long)i * F + o];
    aw[w * F + o] = acc;
    xw[w * F + o] = xi;
    __threadfence_block();  // order LDS write->read within the wave (lgkmcnt)

    float oacc = bias;
#pragma unroll
    for (int k = 0; k < F; k += 4) {
      float4 a4 = *(const float4*)&aw[w * F + k];
      float4 x4 = *(const float4*)&xw[w * F + k];
      oacc += a4.x * wr[k] + a4.y * wr[k + 1] + a4.z * wr[k + 2] + a4.w * wr[k + 3];
      oacc += x4.x * wo[k] + x4.y * wo[k + 1] + x4.z * wo[k + 2] + x4.w * wo[k + 3];
    }
    out[(long long)i * F + o] = fmaxf(oacc, 0.0f);
  }
}

extern "C" void kernel_launch(void* const* d_in, const int* in_sizes, int n_in,
                              void* d_out, int out_size, void* d_ws, size_t ws_size,
                              hipStream_t stream) {
  const float* x      = (const float*)d_in[0];  // [N, 64]
  const float* W_rel  = (const float*)d_in[1];  // [64, 64]
  const float* b_rel  = (const float*)d_in[2];  // [64]
  const float* W_root = (const float*)d_in[3];  // [64, 64]
  const int* edge_index = (const int*)d_in[4];  // [2, E]

  const int n_nodes = in_sizes[0] / F;
  const int n_edges = in_sizes[4] / 2;

  // workspace carve-up (all int32): ~3.8 MB total
  int* deg      = (int*)d_ws;          // [N]
  int* offs     = deg + n_nodes;       // [N+1]
  int* cursor   = offs + n_nodes + 1;  // [N]
  int* partials = cursor + n_nodes;    // [1024] (grid1 <= 256 used)
  int* esrc     = partials + 1024;     // [E]

  float* out = (float*)d_out;

  hipMemsetAsync(deg, 0, (size_t)n_nodes * sizeof(int), stream);

  const int gE = (n_edges + 255) / 256;
  const int gN = (n_nodes + 255) / 256;  // 196 for N=50000 (<= 256 required)

  count_kernel<<<gE, 256, 0, stream>>>(edge_index, deg, n_edges);
  scan1_kernel<<<gN, 256, 0, stream>>>(deg, offs, partials, n_nodes);
  scan2_kernel<<<1, 256, 0, stream>>>(partials, gN);
  scan3_kernel<<<gN, 256, 0, stream>>>(offs, partials, cursor, n_nodes, n_edges);
  fill_kernel<<<gE, 256, 0, stream>>>(edge_index, cursor, esrc, n_edges);

  const int nodes_per_block = 4 * NPW;  // 4 waves/block
  const int gP = (n_nodes + nodes_per_block - 1) / nodes_per_block;
  pull_gemm_kernel<<<gP, 256, 0, stream>>>(x, W_rel, b_rel, W_root, offs, esrc,
                                           out, n_nodes);
}

// Round 3
// 213.583 us; speedup vs baseline: 3.9267x; 1.3917x over previous
//
#include <hip/hip_runtime.h>

#define F 64   // F_IN == F_OUT == 64
#define TILE 64  // nodes per block in the fused kernel
#define PAD 65   // LDS row stride (k-major tiles), +1 breaks power-of-2 conflicts

// ---------------------------------------------------------------------------
// CSR build (unchanged from R2): count -> 3-kernel exclusive scan -> fill.
// ---------------------------------------------------------------------------
__global__ __launch_bounds__(256) void count_kernel(
    const int* __restrict__ edge_index, int* __restrict__ deg, int n_edges) {
  int e = blockIdx.x * 256 + threadIdx.x;
  if (e < n_edges) atomicAdd(&deg[edge_index[n_edges + e]], 1);
}

__global__ __launch_bounds__(256) void scan1_kernel(
    const int* __restrict__ deg, int* __restrict__ offs,
    int* __restrict__ partials, int n) {
  __shared__ int tmp[256];
  const int t = threadIdx.x;
  const int i = blockIdx.x * 256 + t;
  int v = (i < n) ? deg[i] : 0;
  tmp[t] = v;
  __syncthreads();
  for (int d = 1; d < 256; d <<= 1) {
    int add = (t >= d) ? tmp[t - d] : 0;
    __syncthreads();
    tmp[t] += add;
    __syncthreads();
  }
  if (i < n) offs[i] = tmp[t] - v;
  if (t == 255) partials[blockIdx.x] = tmp[255];
}

__global__ __launch_bounds__(256) void scan2_kernel(int* __restrict__ partials,
                                                    int G) {
  __shared__ int tmp[256];
  const int t = threadIdx.x;
  int v = (t < G) ? partials[t] : 0;
  tmp[t] = v;
  __syncthreads();
  for (int d = 1; d < 256; d <<= 1) {
    int add = (t >= d) ? tmp[t - d] : 0;
    __syncthreads();
    tmp[t] += add;
    __syncthreads();
  }
  if (t < G) partials[t] = tmp[t] - v;
}

__global__ __launch_bounds__(256) void scan3_kernel(
    int* __restrict__ offs, const int* __restrict__ partials,
    int* __restrict__ cursor, int n, int n_edges) {
  int i = blockIdx.x * 256 + threadIdx.x;
  if (i < n) {
    int v = offs[i] + partials[i >> 8];
    offs[i] = v;
    cursor[i] = v;
  }
  if (i == 0) offs[n] = n_edges;
}

__global__ __launch_bounds__(256) void fill_kernel(
    const int* __restrict__ edge_index, int* __restrict__ cursor,
    int* __restrict__ esrc, int n_edges) {
  int e = blockIdx.x * 256 + threadIdx.x;
  if (e < n_edges) {
    int src = edge_index[e];
    int dst = edge_index[n_edges + e];
    int pos = atomicAdd(&cursor[dst], 1);
    esrc[pos] = src;
  }
}

// ---------------------------------------------------------------------------
// Transpose weights once per launch: WT[k][o] = W[o][k].  32 KB total ->
// stays L1/L2-resident for the GEMM phase's contiguous float4 reads.
// ---------------------------------------------------------------------------
__global__ __launch_bounds__(256) void transpose_w_kernel(
    const float* __restrict__ W_rel, const float* __restrict__ W_root,
    float* __restrict__ WTrel, float* __restrict__ WTroot) {
  int t = blockIdx.x * 256 + threadIdx.x;
  if (t < F * F) {
    int o = t >> 6, k = t & 63;
    WTrel[k * F + o] = W_rel[t];
    WTroot[k * F + o] = W_root[t];
  }
}

// ---------------------------------------------------------------------------
// Fused pull-gather + GEMM + bias + ReLU over a 64-node tile per block.
//
// Gather (per wave, 16 nodes): lanes = 4 edge-slots x 16 feature-quads.
// One coalesced esrc load per 64 edges; sources distributed via __shfl;
// float4 gathers issued UNCONDITIONALLY (index clamped to 0, add masked) so
// 4 loads are in flight per lane.  shfl_xor(16,32) reduces the slots, then
// slot-0 lanes write the row k-major into aggT[k][r] (PAD=65 -> 2-way banks,
// free).  x self-tile is staged transposed the same way.
//
// GEMM: thread (rq=t>>4, oq=t&15) owns a 4x4 output block.  Per k:
// 8 ds_read_b32 (conflict-free) + 2 global float4 (WT, L1-resident,
// 4x lane-duplicated -> coalesces to 256B) + 32 FMA.
// LDS = 2 * 64*65*4 = 33.3 KB -> 4 blocks/CU.
// ---------------------------------------------------------------------------
__global__ __launch_bounds__(256) void gather_gemm_kernel(
    const float* __restrict__ x,
    const float* __restrict__ WTrel,   // [F][F] k-major
    const float* __restrict__ b_rel,   // [F]
    const float* __restrict__ WTroot,  // [F][F] k-major
    const int* __restrict__ offs,      // [N+1]
    const int* __restrict__ esrc,      // [E]
    float* __restrict__ out, int n_nodes) {
  __shared__ float aggT[F * PAD];
  __shared__ float xT[F * PAD];

  const int t = threadIdx.x;
  const int lane = t & 63;
  const int w = t >> 6;
  const int node0 = blockIdx.x * TILE;

  // ---- phase 1a: aggregate neighbors for nodes [node0+16w, node0+16w+16)
  const int slot = lane >> 4;  // 0..3
  const int fq = lane & 15;    // feature quad: features 4fq..4fq+3
  for (int nn = 0; nn < 16; ++nn) {
    const int i = node0 + w * 16 + nn;  // wave-uniform
    if (i >= n_nodes) break;
    const int start = offs[i];
    const int end = offs[i + 1];
    float4 acc = make_float4(0.f, 0.f, 0.f, 0.f);
    for (int e0 = start; e0 < end; e0 += 64) {
      const int m = min(64, end - e0);
      int my_src = (lane < m) ? esrc[e0 + lane] : 0;
      for (int b = 0; b < m; b += 16) {  // 16 edges per pass, 4 per slot
        const int i0 = b + slot, i1 = b + 4 + slot, i2 = b + 8 + slot,
                  i3 = b + 12 + slot;
        const int s0 = __shfl(my_src, i0, 64);
        const int s1 = __shfl(my_src, i1, 64);
        const int s2 = __shfl(my_src, i2, 64);
        const int s3 = __shfl(my_src, i3, 64);
        // unconditional loads (clamped source) -> 4 in flight per lane
        const float4 f0 = *(const float4*)(x + (long long)(i0 < m ? s0 : 0) * F + fq * 4);
        const float4 f1 = *(const float4*)(x + (long long)(i1 < m ? s1 : 0) * F + fq * 4);
        const float4 f2 = *(const float4*)(x + (long long)(i2 < m ? s2 : 0) * F + fq * 4);
        const float4 f3 = *(const float4*)(x + (long long)(i3 < m ? s3 : 0) * F + fq * 4);
        acc.x += (i0 < m ? f0.x : 0.f); acc.y += (i0 < m ? f0.y : 0.f);
        acc.z += (i0 < m ? f0.z : 0.f); acc.w += (i0 < m ? f0.w : 0.f);
        acc.x += (i1 < m ? f1.x : 0.f); acc.y += (i1 < m ? f1.y : 0.f);
        acc.z += (i1 < m ? f1.z : 0.f); acc.w += (i1 < m ? f1.w : 0.f);
        acc.x += (i2 < m ? f2.x : 0.f); acc.y += (i2 < m ? f2.y : 0.f);
        acc.z += (i2 < m ? f2.z : 0.f); acc.w += (i2 < m ? f2.w : 0.f);
        acc.x += (i3 < m ? f3.x : 0.f); acc.y += (i3 < m ? f3.y : 0.f);
        acc.z += (i3 < m ? f3.z : 0.f); acc.w += (i3 < m ? f3.w : 0.f);
      }
    }
    // reduce the 4 slots: butterfly over lanes^16, ^32
    acc.x += __shfl_xor(acc.x, 16, 64); acc.y += __shfl_xor(acc.y, 16, 64);
    acc.z += __shfl_xor(acc.z, 16, 64); acc.w += __shfl_xor(acc.w, 16, 64);
    acc.x += __shfl_xor(acc.x, 32, 64); acc.y += __shfl_xor(acc.y, 32, 64);
    acc.z += __shfl_xor(acc.z, 32, 64); acc.w += __shfl_xor(acc.w, 32, 64);
    if (slot == 0) {
      const int r = w * 16 + nn;
      aggT[(fq * 4 + 0) * PAD + r] = acc.x;
      aggT[(fq * 4 + 1) * PAD + r] = acc.y;
      aggT[(fq * 4 + 2) * PAD + r] = acc.z;
      aggT[(fq * 4 + 3) * PAD + r] = acc.w;
    }
  }

  // ---- phase 1b: stage the x self-tile transposed (coalesced float4 reads)
  {
    const int c4 = t & 15;        // feature quad
    const int rr = t >> 4;        // 0..15
    for (int p = 0; p < 4; ++p) {
      const int r = p * 16 + rr;
      const int gi = node0 + r;
      float4 v = make_float4(0.f, 0.f, 0.f, 0.f);
      if (gi < n_nodes) v = *(const float4*)(x + (long long)gi * F + c4 * 4);
      xT[(c4 * 4 + 0) * PAD + r] = v.x;
      xT[(c4 * 4 + 1) * PAD + r] = v.y;
      xT[(c4 * 4 + 2) * PAD + r] = v.z;
      xT[(c4 * 4 + 3) * PAD + r] = v.w;
    }
  }
  __syncthreads();

  // ---- phase 2: out[r][o] = relu(b[o] + sum_k aggT[k][r]*WTrel[k][o]
  //                                      + sum_k xT[k][r]*WTroot[k][o])
  const int oq = t & 15, rq = t >> 4;
  const int o0 = oq * 4, r0 = rq * 4;
  const float4 bias = *(const float4*)(b_rel + o0);
  float acc[4][4];
#pragma unroll
  for (int ri = 0; ri < 4; ++ri) {
    acc[ri][0] = bias.x; acc[ri][1] = bias.y;
    acc[ri][2] = bias.z; acc[ri][3] = bias.w;
  }
#pragma unroll 4
  for (int k = 0; k < F; ++k) {
    const float4 wr = *(const float4*)(WTrel + k * F + o0);
    const float4 wo = *(const float4*)(WTroot + k * F + o0);
    const float a0 = aggT[k * PAD + r0 + 0], a1 = aggT[k * PAD + r0 + 1];
    const float a2 = aggT[k * PAD + r0 + 2], a3 = aggT[k * PAD + r0 + 3];
    const float x0 = xT[k * PAD + r0 + 0], x1 = xT[k * PAD + r0 + 1];
    const float x2 = xT[k * PAD + r0 + 2], x3 = xT[k * PAD + r0 + 3];
    acc[0][0] += a0 * wr.x + x0 * wo.x; acc[0][1] += a0 * wr.y + x0 * wo.y;
    acc[0][2] += a0 * wr.z + x0 * wo.z; acc[0][3] += a0 * wr.w + x0 * wo.w;
    acc[1][0] += a1 * wr.x + x1 * wo.x; acc[1][1] += a1 * wr.y + x1 * wo.y;
    acc[1][2] += a1 * wr.z + x1 * wo.z; acc[1][3] += a1 * wr.w + x1 * wo.w;
    acc[2][0] += a2 * wr.x + x2 * wo.x; acc[2][1] += a2 * wr.y + x2 * wo.y;
    acc[2][2] += a2 * wr.z + x2 * wo.z; acc[2][3] += a2 * wr.w + x2 * wo.w;
    acc[3][0] += a3 * wr.x + x3 * wo.x; acc[3][1] += a3 * wr.y + x3 * wo.y;
    acc[3][2] += a3 * wr.z + x3 * wo.z; acc[3][3] += a3 * wr.w + x3 * wo.w;
  }
#pragma unroll
  for (int ri = 0; ri < 4; ++ri) {
    const int gi = node0 + r0 + ri;
    if (gi < n_nodes) {
      float4 o4;
      o4.x = fmaxf(acc[ri][0], 0.f); o4.y = fmaxf(acc[ri][1], 0.f);
      o4.z = fmaxf(acc[ri][2], 0.f); o4.w = fmaxf(acc[ri][3], 0.f);
      *(float4*)(out + (long long)gi * F + o0) = o4;
    }
  }
}

extern "C" void kernel_launch(void* const* d_in, const int* in_sizes, int n_in,
                              void* d_out, int out_size, void* d_ws, size_t ws_size,
                              hipStream_t stream) {
  const float* x      = (const float*)d_in[0];  // [N, 64]
  const float* W_rel  = (const float*)d_in[1];  // [64, 64]
  const float* b_rel  = (const float*)d_in[2];  // [64]
  const float* W_root = (const float*)d_in[3];  // [64, 64]
  const int* edge_index = (const int*)d_in[4];  // [2, E]

  const int n_nodes = in_sizes[0] / F;
  const int n_edges = in_sizes[4] / 2;

  // workspace carve-up (~3.9 MB)
  int* deg      = (int*)d_ws;            // [N]
  int* offs     = deg + n_nodes;         // [N+1]
  int* cursor   = offs + n_nodes + 1;    // [N]
  int* partials = cursor + n_nodes;      // [1024]
  int* esrc     = partials + 1024;       // [E]
  float* WTrel  = (float*)(esrc + n_edges);  // [64*64]
  float* WTroot = WTrel + F * F;             // [64*64]

  float* out = (float*)d_out;

  hipMemsetAsync(deg, 0, (size_t)n_nodes * sizeof(int), stream);

  const int gE = (n_edges + 255) / 256;
  const int gN = (n_nodes + 255) / 256;  // 196 (<=256 required by scan2)
  const int gW = (F * F + 255) / 256;

  transpose_w_kernel<<<gW, 256, 0, stream>>>(W_rel, W_root, WTrel, WTroot);
  count_kernel<<<gE, 256, 0, stream>>>(edge_index, deg, n_edges);
  scan1_kernel<<<gN, 256, 0, stream>>>(deg, offs, partials, n_nodes);
  scan2_kernel<<<1, 256, 0, stream>>>(partials, gN);
  scan3_kernel<<<gN, 256, 0, stream>>>(offs, partials, cursor, n_nodes, n_edges);
  fill_kernel<<<gE, 256, 0, stream>>>(edge_index, cursor, esrc, n_edges);

  const int gP = (n_nodes + TILE - 1) / TILE;  // 782 blocks
  gather_gemm_kernel<<<gP, 256, 0, stream>>>(x, WTrel, b_rel, WTroot, offs,
                                             esrc, out, n_nodes);
}